// Round 1
// baseline (238.871 us; speedup 1.0000x reference)
//
#include <hip/hip_runtime.h>
#include <math.h>

// Problem constants
#define B_ 2
#define F_ 128
#define N_ 192
#define S_ 192
#define H_ 4
#define D_ 64
#define NS_ (N_ * S_)          // 36864
#define SLOPE 0.2f
#define LOG2E 1.4426950408889634f

// Workspace layout (float offsets), 16-float aligned for float4 use
#define OFF_XSUM 0
#define OFF_WSRC 128           // [f*4+h], pre-scaled by LOG2E
#define OFF_WDST 640           // [f*4+h], pre-scaled by LOG2E
#define OFF_CSRC 1152          // (c_src[h] + b_attn) * LOG2E
#define OFF_CDST 1156          // c_dst[h] * LOG2E
#define OFF_SUMG 1168          // [h*64+d], unscaled
#define OFF_SRC  1440          // [b][h][i][s]  (294912)
#define OFF_DST2 296352        // [b][h][j][s]  (294912)
#define OFF_DST1 591264        // [b][h][s][j]  (294912)
#define OFF_ALPHA 886176       // [b][h][i][s]  (294912)
// total 1,181,088 floats = ~4.7 MB

// ---------------- K1: Xsum[f] = sum over (b,n,s) of X ----------------
__global__ __launch_bounds__(256) void k_xsum(const float* __restrict__ X,
                                              float* __restrict__ xsum) {
    int f = blockIdx.x;
    const float4* p0 = (const float4*)(X + (size_t)f * NS_);
    const float4* p1 = (const float4*)(X + (size_t)(F_ + f) * NS_);
    float acc = 0.f;
    for (int i = threadIdx.x; i < NS_ / 4; i += 256) {
        float4 a = p0[i], b = p1[i];
        acc += (a.x + a.y) + (a.z + a.w) + (b.x + b.y) + (b.z + b.w);
    }
    __shared__ float red[4];
    for (int o = 32; o; o >>= 1) acc += __shfl_down(acc, o, 64);
    if ((threadIdx.x & 63) == 0) red[threadIdx.x >> 6] = acc;
    __syncthreads();
    if (threadIdx.x == 0) xsum[f] = (red[0] + red[1]) + (red[2] + red[3]);
}

// ------- K2: w_src/w_dst (×log2e), c terms (×log2e), sum_g -------
__global__ __launch_bounds__(256) void k_small(const float* __restrict__ W_lin,
                                               const float* __restrict__ b_lin,
                                               const float* __restrict__ W_attn,
                                               const float* __restrict__ b_attn,
                                               float* __restrict__ ws) {
    int tid = threadIdx.x;
    float* wsrc = ws + OFF_WSRC;
    float* wdst = ws + OFF_WDST;
    for (int idx = tid; idx < 512; idx += 256) {
        int f = idx >> 2, h = idx & 3;
        const float* wl = W_lin + f * 256 + h * 64;
        float as = 0.f, ad = 0.f;
        for (int d = 0; d < 64; d++) {
            float w = wl[d];
            as += w * W_attn[d];
            ad += w * W_attn[64 + d];
        }
        wsrc[idx] = as * LOG2E;
        wdst[idx] = ad * LOG2E;
    }
    // sum_g[tid]
    {
        float sg = 0.f;
        for (int f = 0; f < 128; f++) sg += ws[OFF_XSUM + f] * W_lin[f * 256 + tid];
        ws[OFF_SUMG + tid] = sg + (float)(B_ * S_ * N_) * b_lin[tid];
    }
    if (tid < 4) {
        float c = 0.f;
        for (int d = 0; d < 64; d++) c += b_lin[tid * 64 + d] * W_attn[d];
        ws[OFF_CSRC + tid] = (c + b_attn[0]) * LOG2E;
    } else if (tid < 8) {
        int h = tid - 4;
        float c = 0.f;
        for (int d = 0; d < 64; d++) c += b_lin[h * 64 + d] * W_attn[64 + d];
        ws[OFF_CDST + h] = c * LOG2E;
    }
}

// ------- K3: projections src[b][h][n][s], dst2[b][h][n][s] -------
__global__ __launch_bounds__(192) void k_proj(const float* __restrict__ X,
                                              float* __restrict__ ws) {
    int n = blockIdx.x, b = blockIdx.y, s = threadIdx.x;
    __shared__ float4 wsl[128], wdl[128];
    if (s < 128) {
        wsl[s] = ((const float4*)(ws + OFF_WSRC))[s];
        wdl[s] = ((const float4*)(ws + OFF_WDST))[s];
    }
    __syncthreads();
    float aS0 = 0, aS1 = 0, aS2 = 0, aS3 = 0;
    float aD0 = 0, aD1 = 0, aD2 = 0, aD3 = 0;
    const float* xp = X + (size_t)(b * F_) * NS_ + n * S_ + s;
#pragma unroll 4
    for (int f = 0; f < 128; f++) {
        float x = xp[(size_t)f * NS_];
        float4 w1 = wsl[f], w2 = wdl[f];
        aS0 += x * w1.x; aS1 += x * w1.y; aS2 += x * w1.z; aS3 += x * w1.w;
        aD0 += x * w2.x; aD1 += x * w2.y; aD2 += x * w2.z; aD3 += x * w2.w;
    }
    float* src = ws + OFF_SRC;
    float* dst2 = ws + OFF_DST2;
    const float* csrc = ws + OFF_CSRC;
    const float* cdst = ws + OFF_CDST;
    float aS[4] = {aS0, aS1, aS2, aS3};
    float aD[4] = {aD0, aD1, aD2, aD3};
#pragma unroll
    for (int h = 0; h < 4; h++) {
        int base = ((b * 4 + h) * 192 + n) * 192 + s;
        src[base] = aS[h] + csrc[h];
        dst2[base] = aD[h] + cdst[h];
    }
}

// ------- K3b: dst1[b][h][s][j] = dst2[b][h][j][s] (batched transpose) -------
__global__ __launch_bounds__(256) void k_transpose(const float* __restrict__ in_,
                                                   float* __restrict__ out_) {
    __shared__ float tile[32][33];
    int bh = blockIdx.z;
    const float* in = in_ + bh * NS_;
    float* out = out_ + bh * NS_;
    int x0 = blockIdx.x * 32, y0 = blockIdx.y * 32;
    int tx = threadIdx.x, ty = threadIdx.y;  // (32, 8)
#pragma unroll
    for (int k = 0; k < 4; k++)
        tile[ty + k * 8][tx] = in[(y0 + ty + k * 8) * 192 + x0 + tx];
    __syncthreads();
#pragma unroll
    for (int k = 0; k < 4; k++)
        out[(x0 + ty + k * 8) * 192 + y0 + tx] = tile[tx][ty + k * 8];
}

// ------- K4: per (b,h,i): column softmax over s, row-sum over j -------
__global__ __launch_bounds__(192) void k_attn(const int* __restrict__ A,
                                              float* __restrict__ ws) {
    int i = blockIdx.x, h = blockIdx.y, b = blockIdx.z;
    int tid = threadIdx.x;
    int bh = b * 4 + h;
    __shared__ float p_sh[192], m_sh[192], z_sh[192];

    const float* src = ws + OFF_SRC;
    float pv = src[(bh * 192 + i) * 192 + tid];
    if (A[tid * 192 + i] == 0) pv = -INFINITY;   // mask is A[s,i], j-independent
    p_sh[tid] = pv;
    __syncthreads();

    // Pass A: thread tid = column j. Column max + sum over s.
    const float* q1 = ws + OFF_DST1 + bh * NS_;  // [s][j]
    float m = -INFINITY;
#pragma unroll 4
    for (int s = 0; s < 192; s++) {
        float e = p_sh[s] + q1[s * 192 + tid];
        e = (e < 0.f) ? SLOPE * e : e;
        m = fmaxf(m, e);
    }
    float zr = 0.f, mm = 0.f;
    if (m > -INFINITY) {
        float Z = 0.f;
#pragma unroll 4
        for (int s = 0; s < 192; s++) {
            float e = p_sh[s] + q1[s * 192 + tid];
            e = (e < 0.f) ? SLOPE * e : e;
            Z += exp2f(e - m);   // masked rows: exp2(-inf) = 0
        }
        zr = 1.f / Z;
        mm = m;
    }
    // all-masked column: (mm,zr)=(0,0) -> contributes exactly 0 (NaN->0 in ref)
    m_sh[tid] = mm;
    z_sh[tid] = zr;
    __syncthreads();

    // Pass B: thread tid = row s. acc = sum_j exp2(E[s,j]-m_j) * zr_j
    const float* q2 = ws + OFF_DST2 + bh * NS_;  // [j][s]
    float acc = 0.f;
#pragma unroll 4
    for (int j = 0; j < 192; j++) {
        float e = pv + q2[j * 192 + tid];
        e = (e < 0.f) ? SLOPE * e : e;
        acc += exp2f(e - m_sh[j]) * z_sh[j];
    }
    float* alpha = ws + OFF_ALPHA;
    alpha[(bh * 192 + i) * 192 + tid] = acc;
}

// ------- K5: out[b, h*64+d, i, s] = alpha[b,h,i,s] * sum_g[h,d] -------
__global__ __launch_bounds__(256) void k_out(const float* __restrict__ ws,
                                             float* __restrict__ out) {
    int idx = blockIdx.x * 256 + threadIdx.x;  // float4 index
    int e0 = idx * 4;
    int s = e0 % 192;
    int i = (e0 / 192) % 192;
    int c = (e0 / 36864) % 256;
    int b = e0 / 9437184;
    int h = c >> 6;
    const float* alpha = ws + OFF_ALPHA;
    float4 a = *(const float4*)(alpha + ((b * 4 + h) * 192 + i) * 192 + s);
    float sg = ws[OFF_SUMG + c];
    float4 o;
    o.x = a.x * sg; o.y = a.y * sg; o.z = a.z * sg; o.w = a.w * sg;
    *(float4*)(out + e0) = o;
}

extern "C" void kernel_launch(void* const* d_in, const int* in_sizes, int n_in,
                              void* d_out, int out_size, void* d_ws, size_t ws_size,
                              hipStream_t stream) {
    const float* X      = (const float*)d_in[0];
    const int*   A      = (const int*)d_in[1];
    const float* W_lin  = (const float*)d_in[2];
    const float* b_lin  = (const float*)d_in[3];
    const float* W_attn = (const float*)d_in[4];
    const float* b_attn = (const float*)d_in[5];
    float* out = (float*)d_out;
    float* ws  = (float*)d_ws;

    k_xsum<<<128, 256, 0, stream>>>(X, ws + OFF_XSUM);
    k_small<<<1, 256, 0, stream>>>(W_lin, b_lin, W_attn, b_attn, ws);
    k_proj<<<dim3(192, 2), 192, 0, stream>>>(X, ws);
    k_transpose<<<dim3(6, 6, 8), dim3(32, 8), 0, stream>>>(ws + OFF_DST2, ws + OFF_DST1);
    k_attn<<<dim3(192, 4, 2), 192, 0, stream>>>(A, ws);
    k_out<<<18432, 256, 0, stream>>>(ws, out);
}

// Round 2
// 206.981 us; speedup vs baseline: 1.1541x; 1.1541x over previous
//
#include <hip/hip_runtime.h>
#include <math.h>

#define B_ 2
#define F_ 128
#define N_ 192
#define S_ 192
#define NS_ (N_ * S_)          // 36864
#define SLOPE 0.2f
#define LOG2E 1.4426950408889634f
#define NEG_INF (-__builtin_inff())

#if defined(__has_builtin)
#if __has_builtin(__builtin_amdgcn_exp2f)
#define EXP2(x) __builtin_amdgcn_exp2f(x)
#else
#define EXP2(x) exp2f(x)
#endif
#else
#define EXP2(x) exp2f(x)
#endif

__device__ __forceinline__ float lrelu(float e) { return fmaxf(e, SLOPE * e); }

// Workspace layout (float offsets)
#define OFF_WSRC 0             // [f*4+h], pre-scaled by LOG2E
#define OFF_WDST 512
#define OFF_CSRC 1024          // (c_src[h] + b_attn) * LOG2E
#define OFF_CDST 1028
#define OFF_SUMG 1040          // [h*64+d]
#define OFF_SRC  1296          // [bh][i][s], MASKED (-inf where A[s,i]==0)
#define OFF_DST2 296208        // [bh][j][s]
#define OFF_Z    591120        // [shalf][bh][i][j], 2*294912
// end = 1,180,944 floats (< proven 1,181,088 budget)
// xsum partials (256 floats) live transiently at OFF_SRC (consumed by k_small
// before k_proj overwrites the region).

// ---------------- K1: xsum partials per (f, b) ----------------
__global__ __launch_bounds__(256) void k_xsum(const float* __restrict__ X,
                                              float* __restrict__ ws) {
    int f = blockIdx.x, b = blockIdx.y, t = threadIdx.x;
    const float4* p = (const float4*)(X + ((size_t)b * F_ + f) * NS_);
    float acc = 0.f;
    for (int i = t; i < NS_ / 4; i += 256) {
        float4 v = p[i];
        acc += (v.x + v.y) + (v.z + v.w);
    }
    for (int o = 32; o; o >>= 1) acc += __shfl_down(acc, o, 64);
    __shared__ float red[4];
    if ((t & 63) == 0) red[t >> 6] = acc;
    __syncthreads();
    if (t == 0) ws[OFF_SRC + b * 128 + f] = (red[0] + red[1]) + (red[2] + red[3]);
}

// ------- K2: weight prep (3 blocks) -------
__global__ __launch_bounds__(256) void k_small(const float* __restrict__ W_lin,
                                               const float* __restrict__ b_lin,
                                               const float* __restrict__ W_attn,
                                               const float* __restrict__ b_attn,
                                               float* __restrict__ ws) {
    int t = threadIdx.x;
    if (blockIdx.x == 0) {
        // wsrc/wdst: 512 cells, 2 per thread
        const float4* wa = (const float4*)W_attn;
        for (int c = t; c < 512; c += 256) {
            int f = c >> 2, h = c & 3;
            const float4* wl = (const float4*)(W_lin + f * 256 + h * 64);
            float as = 0.f, ad = 0.f;
#pragma unroll
            for (int q = 0; q < 16; q++) {
                float4 w = wl[q], a1 = wa[q], a2 = wa[16 + q];
                as += w.x * a1.x + w.y * a1.y + w.z * a1.z + w.w * a1.w;
                ad += w.x * a2.x + w.y * a2.y + w.z * a2.z + w.w * a2.w;
            }
            ws[OFF_WSRC + c] = as * LOG2E;
            ws[OFF_WDST + c] = ad * LOG2E;
        }
    } else if (blockIdx.x == 1) {
        __shared__ float xs[128];
        if (t < 128) xs[t] = ws[OFF_SRC + t] + ws[OFF_SRC + 128 + t];
        __syncthreads();
        float sg = 0.f;
#pragma unroll 4
        for (int f = 0; f < 128; f++) sg += xs[f] * W_lin[f * 256 + t];
        ws[OFF_SUMG + t] = sg + (float)(B_ * S_ * N_) * b_lin[t];
    } else {
        if (t < 4) {
            float c = 0.f;
            for (int d = 0; d < 64; d++) c += b_lin[t * 64 + d] * W_attn[d];
            ws[OFF_CSRC + t] = (c + b_attn[0]) * LOG2E;
        } else if (t < 8) {
            int h = t - 4;
            float c = 0.f;
            for (int d = 0; d < 64; d++) c += b_lin[h * 64 + d] * W_attn[64 + d];
            ws[OFF_CDST + h] = c * LOG2E;
        }
    }
}

// ------- K3: projections; src is MASKED with -inf -------
__global__ __launch_bounds__(192) void k_proj(const float* __restrict__ X,
                                              const int* __restrict__ A,
                                              float* __restrict__ ws) {
    int n = blockIdx.x, b = blockIdx.y, s = threadIdx.x;
    __shared__ float4 wsl[128], wdl[128];
    if (s < 128) {
        wsl[s] = ((const float4*)(ws + OFF_WSRC))[s];
        wdl[s] = ((const float4*)(ws + OFF_WDST))[s];
    }
    __syncthreads();
    float aS0 = 0, aS1 = 0, aS2 = 0, aS3 = 0;
    float aD0 = 0, aD1 = 0, aD2 = 0, aD3 = 0;
    const float* xp = X + (size_t)(b * F_) * NS_ + n * S_ + s;
#pragma unroll 4
    for (int f = 0; f < 128; f++) {
        float x = xp[(size_t)f * NS_];
        float4 w1 = wsl[f], w2 = wdl[f];
        aS0 += x * w1.x; aS1 += x * w1.y; aS2 += x * w1.z; aS3 += x * w1.w;
        aD0 += x * w2.x; aD1 += x * w2.y; aD2 += x * w2.z; aD3 += x * w2.w;
    }
    bool masked = (A[s * 192 + n] == 0);   // mask = A[s, i=n]
    float aS[4] = {aS0, aS1, aS2, aS3};
    float aD[4] = {aD0, aD1, aD2, aD3};
    float* src = ws + OFF_SRC;
    float* dst = ws + OFF_DST2;
#pragma unroll
    for (int h = 0; h < 4; h++) {
        int base = ((b * 4 + h) * 192 + n) * 192 + s;
        src[base] = masked ? NEG_INF : (aS[h] + ws[OFF_CSRC + h]);
        dst[base] = aD[h] + ws[OFF_CDST + h];
    }
}

// ------- K4a: partial Z[sh][bh][i][j] = sum_{s in half} exp2(lrelu(p+q)) -------
#define PADQ 194
__global__ __launch_bounds__(192) void k_attnA(float* __restrict__ ws) {
    int iq = blockIdx.x, bh = blockIdx.y, sh = blockIdx.z;
    int t = threadIdx.x;                 // t = j
    __shared__ float4 p4_sh[96];         // [s'] -> 4 i's
    __shared__ float q_sh[32 * PADQ];    // [s_chunk][j] padded
    const float* src = ws + OFF_SRC + bh * NS_;
    const float* dst = ws + OFF_DST2 + bh * NS_;
    int s0 = sh * 96;
    if (t < 96) {
        int s = s0 + t;
        p4_sh[t] = make_float4(src[(iq * 4 + 0) * 192 + s], src[(iq * 4 + 1) * 192 + s],
                               src[(iq * 4 + 2) * 192 + s], src[(iq * 4 + 3) * 192 + s]);
    }
    float z0 = 0, z1 = 0, z2 = 0, z3 = 0;
    for (int c = 0; c < 3; c++) {
        __syncthreads();
        // stage dst[j][s-chunk] transposed -> q_sh[sc][j]
#pragma unroll
        for (int k = 0; k < 8; k++) {
            int fidx = k * 192 + t;
            int j = fidx >> 3, c4 = fidx & 7;
            float4 v = *(const float4*)(dst + j * 192 + s0 + c * 32 + c4 * 4);
            q_sh[(c4 * 4 + 0) * PADQ + j] = v.x;
            q_sh[(c4 * 4 + 1) * PADQ + j] = v.y;
            q_sh[(c4 * 4 + 2) * PADQ + j] = v.z;
            q_sh[(c4 * 4 + 3) * PADQ + j] = v.w;
        }
        __syncthreads();
#pragma unroll 2
        for (int sc = 0; sc < 32; sc++) {
            float4 p = p4_sh[c * 32 + sc];
            float q = q_sh[sc * PADQ + t];
            z0 += EXP2(lrelu(p.x + q));
            z1 += EXP2(lrelu(p.y + q));
            z2 += EXP2(lrelu(p.z + q));
            z3 += EXP2(lrelu(p.w + q));
        }
    }
    float* zp = ws + OFF_Z + (sh * 8 + bh) * NS_ + (iq * 4) * 192 + t;
    zp[0] = z0; zp[192] = z1; zp[384] = z2; zp[576] = z3;
}

// ------- K4b: alpha-sum over j, fused broadcast-epilogue to out -------
__global__ __launch_bounds__(192) void k_attnB(const float* __restrict__ ws,
                                               float* __restrict__ out) {
    int iq = blockIdx.x, bh = blockIdx.y;
    int t = threadIdx.x;
    int i_loc = t / 48, sq = t % 48;
    __shared__ float zr_sh[4 * 192];
    const float* Z0 = ws + OFF_Z + bh * NS_;
    const float* Z1 = ws + OFF_Z + (8 + bh) * NS_;
#pragma unroll
    for (int k = 0; k < 4; k++) {
        int idx = (iq * 4 + k) * 192 + t;
        float Zt = Z0[idx] + Z1[idx];
        zr_sh[k * 192 + t] = (Zt != 0.f) ? (1.0f / Zt) : 0.f;
    }
    __syncthreads();
    const float* src = ws + OFF_SRC + bh * NS_;
    const float* dst = ws + OFF_DST2 + bh * NS_;
    int i = iq * 4 + i_loc, s0 = sq * 4;
    float4 pv = *(const float4*)(src + i * 192 + s0);
    float4 acc = make_float4(0.f, 0.f, 0.f, 0.f);
    const float* zrow = zr_sh + i_loc * 192;
#pragma unroll 4
    for (int j = 0; j < 192; j++) {
        float4 q = *(const float4*)(dst + j * 192 + s0);
        float zr = zrow[j];
        acc.x += EXP2(lrelu(pv.x + q.x)) * zr;
        acc.y += EXP2(lrelu(pv.y + q.y)) * zr;
        acc.z += EXP2(lrelu(pv.z + q.z)) * zr;
        acc.w += EXP2(lrelu(pv.w + q.w)) * zr;
    }
    // out[b][h*64+d][i][s] = acc * sum_g[h][d]
    int b = bh >> 2, h = bh & 3;
    const float* sg = ws + OFF_SUMG + h * 64;
    float* op = out + ((size_t)(b * 256 + h * 64) * 192 + i) * 192 + s0;
#pragma unroll 4
    for (int d = 0; d < 64; d++) {
        float g = sg[d];
        float4 o = make_float4(acc.x * g, acc.y * g, acc.z * g, acc.w * g);
        *(float4*)(op + (size_t)d * NS_) = o;
    }
}

extern "C" void kernel_launch(void* const* d_in, const int* in_sizes, int n_in,
                              void* d_out, int out_size, void* d_ws, size_t ws_size,
                              hipStream_t stream) {
    const float* X      = (const float*)d_in[0];
    const int*   A      = (const int*)d_in[1];
    const float* W_lin  = (const float*)d_in[2];
    const float* b_lin  = (const float*)d_in[3];
    const float* W_attn = (const float*)d_in[4];
    const float* b_attn = (const float*)d_in[5];
    float* out = (float*)d_out;
    float* ws  = (float*)d_ws;

    k_xsum<<<dim3(128, 2), 256, 0, stream>>>(X, ws);
    k_small<<<3, 256, 0, stream>>>(W_lin, b_lin, W_attn, b_attn, ws);
    k_proj<<<dim3(192, 2), 192, 0, stream>>>(X, A, ws);
    k_attnA<<<dim3(48, 8, 2), 192, 0, stream>>>(ws);
    k_attnB<<<dim3(48, 8), 192, 0, stream>>>(ws, out);
}

// Round 3
// 167.544 us; speedup vs baseline: 1.4257x; 1.2354x over previous
//
#include <hip/hip_runtime.h>
#include <math.h>

#define B_ 2
#define F_ 128
#define N_ 192
#define S_ 192
#define NS_ (N_ * S_)          // 36864
#define SLOPE 0.2f
#define LOG2E 1.4426950408889634f
#define NEG_INF (-__builtin_inff())

#if defined(__has_builtin)
#if __has_builtin(__builtin_amdgcn_exp2f)
#define EXP2(x) __builtin_amdgcn_exp2f(x)
#else
#define EXP2(x) exp2f(x)
#endif
#else
#define EXP2(x) exp2f(x)
#endif

__device__ __forceinline__ float lrelu(float e) { return fmaxf(e, SLOPE * e); }

// Workspace layout (float offsets) — total 886,288 floats = 3.55 MB
#define OFF_WSRC 0             // [f*4+h] * LOG2E
#define OFF_WDST 512
#define OFF_CSRC 1024          // (c_src[h] + b_attn) * LOG2E
#define OFF_CDST 1028
#define OFF_SUMG 1040          // [h*64+d]
#define OFF_XSUM 1296          // [b][f]
#define OFF_SRC  1552          // [bh][i][s], MASKED (-inf where A[s,i]==0)
#define OFF_DST2 (OFF_SRC + 8 * NS_)   // [bh][j][s]
#define OFF_DST1 (OFF_DST2 + 8 * NS_)  // [bh][s][j]

// ---------------- K1: xsum partials (blk<256) + weight prep (256) + c prep (257) ----
__global__ __launch_bounds__(256) void k1(const float* __restrict__ X,
                                          const float* __restrict__ W_lin,
                                          const float* __restrict__ b_lin,
                                          const float* __restrict__ W_attn,
                                          const float* __restrict__ b_attn,
                                          float* __restrict__ ws) {
    int blk = blockIdx.x, t = threadIdx.x;
    if (blk < 256) {
        int f = blk & 127, b = blk >> 7;
        const float4* p = (const float4*)(X + ((size_t)b * F_ + f) * NS_);
        float acc = 0.f;
        for (int i = t; i < NS_ / 4; i += 256) {
            float4 v = p[i];
            acc += (v.x + v.y) + (v.z + v.w);
        }
        for (int o = 32; o; o >>= 1) acc += __shfl_down(acc, o, 64);
        __shared__ float red[4];
        if ((t & 63) == 0) red[t >> 6] = acc;
        __syncthreads();
        if (t == 0) ws[OFF_XSUM + b * 128 + f] = (red[0] + red[1]) + (red[2] + red[3]);
    } else if (blk == 256) {
        const float4* wa = (const float4*)W_attn;
        for (int c = t; c < 512; c += 256) {
            int f = c >> 2, h = c & 3;
            const float4* wl = (const float4*)(W_lin + f * 256 + h * 64);
            float as = 0.f, ad = 0.f;
#pragma unroll
            for (int q = 0; q < 16; q++) {
                float4 w = wl[q], a1 = wa[q], a2 = wa[16 + q];
                as += w.x * a1.x + w.y * a1.y + w.z * a1.z + w.w * a1.w;
                ad += w.x * a2.x + w.y * a2.y + w.z * a2.z + w.w * a2.w;
            }
            ws[OFF_WSRC + c] = as * LOG2E;
            ws[OFF_WDST + c] = ad * LOG2E;
        }
    } else {
        if (t < 4) {
            float c = 0.f;
            for (int d = 0; d < 64; d++) c += b_lin[t * 64 + d] * W_attn[d];
            ws[OFF_CSRC + t] = (c + b_attn[0]) * LOG2E;
        } else if (t < 8) {
            int h = t - 4;
            float c = 0.f;
            for (int d = 0; d < 64; d++) c += b_lin[h * 64 + d] * W_attn[64 + d];
            ws[OFF_CDST + h] = c * LOG2E;
        }
    }
}

// ------- K2: projection (blk<384, f split across 8 wave-chunks) + sum_g (blk==384) --
__global__ __launch_bounds__(512) void k2(const float* __restrict__ X,
                                          const int* __restrict__ A,
                                          const float* __restrict__ W_lin,
                                          const float* __restrict__ b_lin,
                                          float* __restrict__ ws) {
    __shared__ float4 wsl[128], wdl[128];
    __shared__ __align__(16) float red[192 * 65];   // padded: bank stride 65
    int t = threadIdx.x;
    int blk = blockIdx.x;
    if (blk < 384) {
        int n = blk % 192, b = blk / 192;
        if (t < 128) {
            wsl[t] = ((const float4*)(ws + OFF_WSRC))[t];
            wdl[t] = ((const float4*)(ws + OFF_WDST))[t];
        }
        __syncthreads();
        int fq = t >> 6, lane = t & 63;
        float aS[4][3] = {{0}}, aD[4][3] = {{0}};
        const float* xp = X + (size_t)(b * F_) * NS_ + n * S_ + lane;
        int f0 = fq * 16;
#pragma unroll 4
        for (int fi = 0; fi < 16; fi++) {
            const float* xf = xp + (size_t)(f0 + fi) * NS_;
            float x0 = xf[0], x1 = xf[64], x2 = xf[128];
            float4 w1 = wsl[f0 + fi], w2 = wdl[f0 + fi];
            aS[0][0] += x0 * w1.x; aS[0][1] += x1 * w1.x; aS[0][2] += x2 * w1.x;
            aS[1][0] += x0 * w1.y; aS[1][1] += x1 * w1.y; aS[1][2] += x2 * w1.y;
            aS[2][0] += x0 * w1.z; aS[2][1] += x1 * w1.z; aS[2][2] += x2 * w1.z;
            aS[3][0] += x0 * w1.w; aS[3][1] += x1 * w1.w; aS[3][2] += x2 * w1.w;
            aD[0][0] += x0 * w2.x; aD[0][1] += x1 * w2.x; aD[0][2] += x2 * w2.x;
            aD[1][0] += x0 * w2.y; aD[1][1] += x1 * w2.y; aD[1][2] += x2 * w2.y;
            aD[2][0] += x0 * w2.z; aD[2][1] += x1 * w2.z; aD[2][2] += x2 * w2.z;
            aD[3][0] += x0 * w2.w; aD[3][1] += x1 * w2.w; aD[3][2] += x2 * w2.w;
        }
#pragma unroll
        for (int h = 0; h < 4; h++)
#pragma unroll
            for (int k = 0; k < 3; k++) {
                int s = lane + 64 * k;
                red[s * 65 + fq * 8 + h] = aS[h][k];
                red[s * 65 + fq * 8 + 4 + h] = aD[h][k];
            }
        __syncthreads();
        if (t < 192) {
            int s = t;
            bool masked = (A[s * 192 + n] == 0);   // mask = A[s, i=n]
#pragma unroll
            for (int h = 0; h < 4; h++) {
                float vS = 0.f, vD = 0.f;
#pragma unroll
                for (int q = 0; q < 8; q++) {
                    vS += red[s * 65 + q * 8 + h];
                    vD += red[s * 65 + q * 8 + 4 + h];
                }
                float sv = vS + ws[OFF_CSRC + h];
                float dv = vD + ws[OFF_CDST + h];
                int bh = b * 4 + h;
                ws[OFF_SRC + bh * NS_ + n * 192 + s] = masked ? NEG_INF : sv;
                ws[OFF_DST2 + bh * NS_ + n * 192 + s] = dv;
                ws[OFF_DST1 + bh * NS_ + s * 192 + n] = dv;  // scattered, L2-absorbed
            }
        }
    } else {
        // sum_g[c] = sum_f xs[f] * W_lin[f][c] + 73728 * b_lin[c]
        float* xs = (float*)wsl;
        if (t < 128) xs[t] = ws[OFF_XSUM + t] + ws[OFF_XSUM + 128 + t];
        __syncthreads();
        float acc = 0.f;
        for (int ch = 0; ch < 8; ch++) {
            const float4* s4 = (const float4*)(W_lin + ch * 4096);
            ((float4*)red)[t] = s4[t];
            ((float4*)red)[512 + t] = s4[512 + t];
            __syncthreads();
            if (t < 256) {
#pragma unroll
                for (int fi = 0; fi < 16; fi++)
                    acc += xs[ch * 16 + fi] * red[fi * 256 + t];
            }
            __syncthreads();
        }
        if (t < 256) ws[OFF_SUMG + t] = acc + 73728.f * b_lin[t];
    }
}

// ------- K3: fused attention: Z (pass A) -> zr -> alpha-sum (pass B) -> epilogue ----
__global__ __launch_bounds__(768) void k3(const float* __restrict__ ws,
                                          float* __restrict__ out) {
    int iq = blockIdx.x, bh = blockIdx.y;
    int t = threadIdx.x;                    // 768 threads = 12 waves
    __shared__ float p_sh[768];             // [i_loc][s]
    __shared__ float zpart[4 * 768];        // [sq][i_loc][j]
    __shared__ float zr_sh[768];            // [i_loc][j]
    __shared__ float sg_sh[64];
    const float* src = ws + OFF_SRC + bh * NS_;
    const float* d1 = ws + OFF_DST1 + bh * NS_;
    const float* d2 = ws + OFF_DST2 + bh * NS_;
    int h = bh & 3;
    if (t < 64) sg_sh[t] = ws[OFF_SUMG + h * 64 + t];
    p_sh[t] = src[iq * 768 + t];            // 4 contiguous i-rows
    __syncthreads();

    // Pass A: Z[i][j] partials, s split 4 ways
    {
        int sq = t / 192, j = t - sq * 192;
        float z0 = 0, z1 = 0, z2 = 0, z3 = 0;
        const float* d1p = d1 + j;
#pragma unroll 4
        for (int s = sq * 48; s < sq * 48 + 48; s++) {
            float q = d1p[s * 192];         // coalesced
            z0 += EXP2(lrelu(p_sh[s] + q));
            z1 += EXP2(lrelu(p_sh[192 + s] + q));
            z2 += EXP2(lrelu(p_sh[384 + s] + q));
            z3 += EXP2(lrelu(p_sh[576 + s] + q));
        }
        float* zp = zpart + sq * 768 + j;
        zp[0] = z0; zp[192] = z1; zp[384] = z2; zp[576] = z3;
    }
    __syncthreads();
    {
        float Z = zpart[t] + zpart[768 + t] + zpart[1536 + t] + zpart[2304 + t];
        zr_sh[t] = (Z != 0.f) ? (1.f / Z) : 0.f;   // all-masked column -> 0
    }
    __syncthreads();

    // Pass B: alpha_sum[i][s] + fused broadcast epilogue
    {
        int i_loc = t / 192, s = t - i_loc * 192;
        float pv = p_sh[t];
        const float* zr = zr_sh + i_loc * 192;
        float acc = 0.f;
#pragma unroll 4
        for (int j = 0; j < 192; j++) {
            float q = d2[j * 192 + s];      // coalesced
            acc += EXP2(lrelu(pv + q)) * zr[j];
        }
        int b = bh >> 2;
        int i = iq * 4 + i_loc;
        float* op = out + (((size_t)(b * 256 + h * 64)) * 192 + i) * 192 + s;
#pragma unroll 8
        for (int d = 0; d < 64; d++)
            op[(size_t)d * NS_] = acc * sg_sh[d];
    }
}

extern "C" void kernel_launch(void* const* d_in, const int* in_sizes, int n_in,
                              void* d_out, int out_size, void* d_ws, size_t ws_size,
                              hipStream_t stream) {
    const float* X      = (const float*)d_in[0];
    const int*   A      = (const int*)d_in[1];
    const float* W_lin  = (const float*)d_in[2];
    const float* b_lin  = (const float*)d_in[3];
    const float* W_attn = (const float*)d_in[4];
    const float* b_attn = (const float*)d_in[5];
    float* out = (float*)d_out;
    float* ws  = (float*)d_ws;

    k1<<<258, 256, 0, stream>>>(X, W_lin, b_lin, W_attn, b_attn, ws);
    k2<<<385, 512, 0, stream>>>(X, A, W_lin, b_lin, ws);
    k3<<<dim3(48, 8), 768, 0, stream>>>(ws, out);
}

// Round 4
// 150.870 us; speedup vs baseline: 1.5833x; 1.1105x over previous
//
#include <hip/hip_runtime.h>
#include <math.h>

#define B_ 2
#define F_ 128
#define N_ 192
#define S_ 192
#define NS_ (N_ * S_)          // 36864
#define SLOPE 0.2f
#define LOG2E 1.4426950408889634f
#define NEG_INF (-__builtin_inff())

#if defined(__has_builtin)
#if __has_builtin(__builtin_amdgcn_exp2f)
#define EXP2(x) __builtin_amdgcn_exp2f(x)
#else
#define EXP2(x) exp2f(x)
#endif
#else
#define EXP2(x) exp2f(x)
#endif

__device__ __forceinline__ float lrelu(float e) { return fmaxf(e, SLOPE * e); }

// Workspace layout (float offsets) — total ~887,056 floats = 3.55 MB
#define OFF_WSRC 0             // [f*4+h] * LOG2E
#define OFF_WDST 512
#define OFF_CSRC 1024          // (c_src[h] + b_attn) * LOG2E
#define OFF_CDST 1028
#define OFF_SUMG 1040          // [h*64+d]
#define OFF_PART 1296          // [sq 4][b 2][f 128] xsum partials
#define OFF_SRC  2320          // [bh][i][s], MASKED (-inf where A[s,i]==0)
#define OFF_DST2 (OFF_SRC + 8 * NS_)   // [bh][j][s]
#define OFF_DST1 (OFF_DST2 + 8 * NS_)  // [bh][s][j]

// ---- kPre: blocks 0..1023 xsum partials; 1024: wsrc/wdst; 1025: csrc/cdst ----
__global__ __launch_bounds__(256) void kPre(const float* __restrict__ X,
                                            const float* __restrict__ W_lin,
                                            const float* __restrict__ b_lin,
                                            const float* __restrict__ W_attn,
                                            const float* __restrict__ b_attn,
                                            float* __restrict__ ws) {
    int blk = blockIdx.x, t = threadIdx.x;
    if (blk < 1024) {
        int sq = blk & 3, f = (blk >> 2) & 127, b = blk >> 9;
        const float4* p = (const float4*)(X + ((size_t)(b * F_ + f)) * NS_ + sq * 9216);
        float acc = 0.f;
#pragma unroll
        for (int k = 0; k < 9; k++) {
            float4 v = p[t + k * 256];
            acc += (v.x + v.y) + (v.z + v.w);
        }
        for (int o = 32; o; o >>= 1) acc += __shfl_down(acc, o, 64);
        __shared__ float red[4];
        if ((t & 63) == 0) red[t >> 6] = acc;
        __syncthreads();
        if (t == 0)
            ws[OFF_PART + sq * 256 + b * 128 + f] = (red[0] + red[1]) + (red[2] + red[3]);
    } else if (blk == 1024) {
        const float4* wa = (const float4*)W_attn;
        for (int c = t; c < 512; c += 256) {
            int f = c >> 2, h = c & 3;
            const float4* wl = (const float4*)(W_lin + f * 256 + h * 64);
            float as = 0.f, ad = 0.f;
#pragma unroll
            for (int q = 0; q < 16; q++) {
                float4 w = wl[q], a1 = wa[q], a2 = wa[16 + q];
                as += w.x * a1.x + w.y * a1.y + w.z * a1.z + w.w * a1.w;
                ad += w.x * a2.x + w.y * a2.y + w.z * a2.z + w.w * a2.w;
            }
            ws[OFF_WSRC + c] = as * LOG2E;
            ws[OFF_WDST + c] = ad * LOG2E;
        }
    } else {
        if (t < 4) {
            float c = 0.f;
            for (int d = 0; d < 64; d++) c += b_lin[t * 64 + d] * W_attn[d];
            ws[OFF_CSRC + t] = (c + b_attn[0]) * LOG2E;
        } else if (t < 8) {
            int h = t - 4;
            float c = 0.f;
            for (int d = 0; d < 64; d++) c += b_lin[h * 64 + d] * W_attn[64 + d];
            ws[OFF_CDST + h] = c * LOG2E;
        }
    }
}

// ---- kProj: blocks < 1152: (n, b, s-chunk of 64), f split 4-way across waves;
//      block 1152: sum_g ----
__global__ __launch_bounds__(256) void kProj(const float* __restrict__ X,
                                             const int* __restrict__ A,
                                             const float* __restrict__ W_lin,
                                             const float* __restrict__ b_lin,
                                             float* __restrict__ ws) {
    __shared__ float4 wsl[128], wdl[128];
    __shared__ float red[4 * 64 * 9];     // [fq][lane][8 +1 pad]
    __shared__ float xs[128];
    __shared__ float wbuf[4096];
    int t = threadIdx.x, blk = blockIdx.x;
    if (blk < 1152) {
        int n = blk % 192, bsc = blk / 192;
        int b = bsc / 3, sc = bsc % 3;
        if (t < 128) {
            wsl[t] = ((const float4*)(ws + OFF_WSRC))[t];
            wdl[t] = ((const float4*)(ws + OFF_WDST))[t];
        }
        __syncthreads();
        int fq = t >> 6, lane = t & 63;
        int s = sc * 64 + lane;
        float aS[4] = {0, 0, 0, 0}, aD[4] = {0, 0, 0, 0};
        const float* xp = X + (size_t)(b * F_) * NS_ + n * S_ + s;
        int f0 = fq * 32;
#pragma unroll 8
        for (int fi = 0; fi < 32; fi++) {
            float x = xp[(size_t)(f0 + fi) * NS_];
            float4 w1 = wsl[f0 + fi], w2 = wdl[f0 + fi];
            aS[0] += x * w1.x; aS[1] += x * w1.y; aS[2] += x * w1.z; aS[3] += x * w1.w;
            aD[0] += x * w2.x; aD[1] += x * w2.y; aD[2] += x * w2.z; aD[3] += x * w2.w;
        }
        float* rp = red + t * 9;
#pragma unroll
        for (int h = 0; h < 4; h++) { rp[h] = aS[h]; rp[4 + h] = aD[h]; }
        __syncthreads();
        // 512 cells: [s_loc 64][k 8]; k<4 -> src h=k, k>=4 -> dst h=k-4
#pragma unroll
        for (int c = t; c < 512; c += 256) {
            int s_loc = c >> 3, k = c & 7;
            float v = red[s_loc * 9 + k] + red[(64 + s_loc) * 9 + k] +
                      red[(128 + s_loc) * 9 + k] + red[(192 + s_loc) * 9 + k];
            int ss = sc * 64 + s_loc;
            if (k < 4) {
                int bh = b * 4 + k;
                bool masked = (A[ss * 192 + n] == 0);   // mask = A[s, i=n]
                ws[OFF_SRC + bh * NS_ + n * 192 + ss] =
                    masked ? NEG_INF : (v + ws[OFF_CSRC + k]);
            } else {
                int h = k - 4, bh = b * 4 + h;
                float dv = v + ws[OFF_CDST + h];
                ws[OFF_DST2 + bh * NS_ + n * 192 + ss] = dv;
                ws[OFF_DST1 + bh * NS_ + ss * 192 + n] = dv;  // scatter, L2
            }
        }
    } else {
        // sum_g[c] = sum_f xsum[f] * W_lin[f][c] + 73728 * b_lin[c]
        if (t < 128) {
            float v = 0.f;
#pragma unroll
            for (int q = 0; q < 8; q++) v += ws[OFF_PART + q * 128 + t];
            xs[t] = v;
        }
        float acc = 0.f;
        for (int ch = 0; ch < 8; ch++) {
            const float4* s4 = (const float4*)(W_lin + ch * 4096);
            __syncthreads();
#pragma unroll
            for (int k = 0; k < 4; k++) ((float4*)wbuf)[t + k * 256] = s4[t + k * 256];
            __syncthreads();
#pragma unroll
            for (int fi = 0; fi < 16; fi++) acc += xs[ch * 16 + fi] * wbuf[fi * 256 + t];
        }
        ws[OFF_SUMG + t] = acc + 73728.f * b_lin[t];
    }
}

// ---- kAttn: 768 blocks (bh = blk&7 XCD swizzle, 2 i rows each), 384 thr ----
__global__ __launch_bounds__(384) void kAttn(const float* __restrict__ ws,
                                             float* __restrict__ out) {
    int blk = blockIdx.x, t = threadIdx.x;
    int bh = blk & 7, iq = blk >> 3;        // iq 0..95
    int b = bh >> 2, h = bh & 3;
    __shared__ float p_sh[384];             // [i_loc][s]
    __shared__ float zpart[2 * 384];        // [sq][i_loc][j]
    __shared__ float zr_sh[384];            // [i_loc][j]
    __shared__ float sg_sh[64];
    const float* src = ws + OFF_SRC + bh * NS_;
    const float* d1 = ws + OFF_DST1 + bh * NS_;
    const float* d2 = ws + OFF_DST2 + bh * NS_;
    if (t < 64) sg_sh[t] = ws[OFF_SUMG + h * 64 + t];
    p_sh[t] = src[iq * 384 + t];            // 2 contiguous i-rows
    __syncthreads();

    // Pass A: Z[i][j], s split in halves of 96
    {
        int sq = t / 192, j = t - sq * 192;
        float z0 = 0.f, z1 = 0.f;
        const float* d1p = d1 + j;
#pragma unroll 8
        for (int s = sq * 96; s < sq * 96 + 96; s++) {
            float q = d1p[s * 192];         // coalesced
            z0 += EXP2(lrelu(p_sh[s] + q));
            z1 += EXP2(lrelu(p_sh[192 + s] + q));
        }
        zpart[sq * 384 + j] = z0;
        zpart[sq * 384 + 192 + j] = z1;
    }
    __syncthreads();
    {
        float Z = zpart[t] + zpart[384 + t];
        zr_sh[t] = (Z != 0.f) ? (1.f / Z) : 0.f;   // all-masked column -> 0
    }
    __syncthreads();

    // Pass B: alpha-sum over j + fused broadcast epilogue
    {
        int i_loc = t / 192, s = t - i_loc * 192;
        float pv = p_sh[t];
        const float* zr = zr_sh + i_loc * 192;
        float acc = 0.f;
#pragma unroll 8
        for (int j = 0; j < 192; j++) {
            float q = d2[j * 192 + s];      // coalesced
            acc += EXP2(lrelu(pv + q)) * zr[j];
        }
        int i = iq * 2 + i_loc;
        float* op = out + (((size_t)(b * 256 + h * 64)) * 192 + i) * 192 + s;
#pragma unroll 8
        for (int d = 0; d < 64; d++)
            op[(size_t)d * NS_] = acc * sg_sh[d];
    }
}

extern "C" void kernel_launch(void* const* d_in, const int* in_sizes, int n_in,
                              void* d_out, int out_size, void* d_ws, size_t ws_size,
                              hipStream_t stream) {
    const float* X      = (const float*)d_in[0];
    const int*   A      = (const int*)d_in[1];
    const float* W_lin  = (const float*)d_in[2];
    const float* b_lin  = (const float*)d_in[3];
    const float* W_attn = (const float*)d_in[4];
    const float* b_attn = (const float*)d_in[5];
    float* out = (float*)d_out;
    float* ws  = (float*)d_ws;

    kPre<<<1026, 256, 0, stream>>>(X, W_lin, b_lin, W_attn, b_attn, ws);
    kProj<<<1153, 256, 0, stream>>>(X, A, W_lin, b_lin, ws);
    kAttn<<<768, 384, 0, stream>>>(ws, out);
}